// Round 5
// baseline (10891.933 us; speedup 1.0000x reference)
//
#include <hip/hip_runtime.h>
#include <cstdint>
#include <cstddef>

#define P_N  2048
#define OBS_N 512
#define H_N  2048
#define G3H  6144

__device__ __forceinline__ float wave_sum(float v) {
#pragma unroll
  for (int off = 32; off > 0; off >>= 1) v += __shfl_xor(v, off);
  return v;
}
__device__ __forceinline__ float wave_max(float v) {
#pragma unroll
  for (int off = 32; off > 0; off >>= 1) v = fmaxf(v, __shfl_xor(v, off));
  return v;
}

// ---------------------------------------------------------------------------
// Kernel 1: gi = obs @ w_ih.T + b_ih   (fp32, 128x128 tile, 8x8 per thread)
// ---------------------------------------------------------------------------
__global__ __launch_bounds__(256, 2) void gi_gemm(
    const float* __restrict__ A,    // obs [2048][512]
    const float* __restrict__ B,    // w_ih [6144][512]
    const float* __restrict__ bias, // b_ih [6144]
    float* __restrict__ C)          // gi [2048][6144]
{
  constexpr int BM = 128, BK = 32, LDP = BM + 4;
  __shared__ float As[BK][LDP];
  __shared__ float Bs[BK][LDP];
  const int tid = threadIdx.x;
  const int bm = blockIdx.y * BM;
  const int bn = blockIdx.x * BM;
  const int tx = tid & 15, ty = tid >> 4;
  const int lrow = tid >> 3;          // 0..31
  const int lk4  = (tid & 7) << 2;    // 0..28

  float acc[8][8];
#pragma unroll
  for (int i = 0; i < 8; ++i)
#pragma unroll
    for (int j = 0; j < 8; ++j) acc[i][j] = 0.f;

  for (int k0 = 0; k0 < OBS_N; k0 += BK) {
#pragma unroll
    for (int i = 0; i < 4; ++i) {
      const int r = lrow + 32 * i;
      float4 av = *(const float4*)(A + (size_t)(bm + r) * OBS_N + k0 + lk4);
      float4 bv = *(const float4*)(B + (size_t)(bn + r) * OBS_N + k0 + lk4);
      As[lk4 + 0][r] = av.x; As[lk4 + 1][r] = av.y;
      As[lk4 + 2][r] = av.z; As[lk4 + 3][r] = av.w;
      Bs[lk4 + 0][r] = bv.x; Bs[lk4 + 1][r] = bv.y;
      Bs[lk4 + 2][r] = bv.z; Bs[lk4 + 3][r] = bv.w;
    }
    __syncthreads();
#pragma unroll
    for (int k = 0; k < BK; ++k) {
      float4 a0 = *(const float4*)&As[k][ty * 4];
      float4 a1 = *(const float4*)&As[k][64 + ty * 4];
      float4 b0 = *(const float4*)&Bs[k][tx * 4];
      float4 b1 = *(const float4*)&Bs[k][64 + tx * 4];
      float a[8] = {a0.x, a0.y, a0.z, a0.w, a1.x, a1.y, a1.z, a1.w};
      float b[8] = {b0.x, b0.y, b0.z, b0.w, b1.x, b1.y, b1.z, b1.w};
#pragma unroll
      for (int i = 0; i < 8; ++i)
#pragma unroll
        for (int j = 0; j < 8; ++j)
          acc[i][j] = fmaf(a[i], b[j], acc[i][j]);
    }
    __syncthreads();
  }

  float4 bs0 = *(const float4*)(bias + bn + tx * 4);
  float4 bs1 = *(const float4*)(bias + bn + 64 + tx * 4);
  const float bb[8] = {bs0.x, bs0.y, bs0.z, bs0.w, bs1.x, bs1.y, bs1.z, bs1.w};
#pragma unroll
  for (int i = 0; i < 8; ++i) {
    const int row = bm + ((i < 4) ? (ty * 4 + i) : (64 + ty * 4 + i - 4));
    float4 o0 = {acc[i][0] + bb[0], acc[i][1] + bb[1], acc[i][2] + bb[2], acc[i][3] + bb[3]};
    float4 o1 = {acc[i][4] + bb[4], acc[i][5] + bb[5], acc[i][6] + bb[6], acc[i][7] + bb[7]};
    *(float4*)(C + (size_t)row * G3H + bn + tx * 4) = o0;
    *(float4*)(C + (size_t)row * G3H + bn + 64 + tx * 4) = o1;
  }
}

// ---------------------------------------------------------------------------
// Kernel 2: sequential GRU scan. 256 persistent WGs x 512 threads, 1 WG/CU.
// WG g owns h indices [g*8, g*8+8); wave w owns index j=g*8+w and its 3 gate
// rows of w_hh.
//
// R5: weights live in PHYSICAL AGPRs a0..a95, written once at entry with
// v_accvgpr_write_b32 and re-read every step with v_accvgpr_read_b32 — all
// volatile asm, each statement clobbering its register (usage metadata counts
// the AGPRs; RA avoids them). R1-R4 proved the compiler's remat/sink
// heuristic re-streams 50 MB/step of weights from L2/L3 (5 us/step) no
// matter how the source parks them (VGPR_Count pinned at 72-80 through plain
// regs, +v pins, virtual-"a" parking, and (512,1) bounds). Physical regs
// cannot be rematerialized or spilled by the allocator.
// ---------------------------------------------------------------------------
#define AGW(reg, val) \
  asm volatile("v_accvgpr_write_b32 " reg ", %0" :: "v"(val) : reg)
#define AGR(reg, dst) \
  asm volatile("v_accvgpr_read_b32 %0, " reg : "=v"(dst) :: reg)

#define LOADK_(koff, r0a,r0b,r0c,r0d, r1a,r1b,r1c,r1d, r2a,r2b,r2c,r2d) do { \
    float4 A_ = *(const float4*)(p0 + (koff) * 256 + l4); \
    float4 B_ = *(const float4*)(p1 + (koff) * 256 + l4); \
    float4 C_ = *(const float4*)(p2 + (koff) * 256 + l4); \
    AGW(r0a, A_.x); AGW(r0b, A_.y); AGW(r0c, A_.z); AGW(r0d, A_.w); \
    AGW(r1a, B_.x); AGW(r1b, B_.y); AGW(r1c, B_.z); AGW(r1d, B_.w); \
    AGW(r2a, C_.x); AGW(r2b, C_.y); AGW(r2c, C_.z); AGW(r2d, C_.w); \
  } while (0)

#define GEMVK_(koff, r0a,r0b,r0c,r0d, r1a,r1b,r1c,r1d, r2a,r2b,r2c,r2d) do { \
    float4 hv = *(const float4*)&hbuf[(koff) * 256 + l4]; \
    float tw; \
    AGR(r0a, tw); acc0 = fmaf(tw, hv.x, acc0); \
    AGR(r0b, tw); acc0 = fmaf(tw, hv.y, acc0); \
    AGR(r0c, tw); acc0 = fmaf(tw, hv.z, acc0); \
    AGR(r0d, tw); acc0 = fmaf(tw, hv.w, acc0); \
    AGR(r1a, tw); acc1 = fmaf(tw, hv.x, acc1); \
    AGR(r1b, tw); acc1 = fmaf(tw, hv.y, acc1); \
    AGR(r1c, tw); acc1 = fmaf(tw, hv.z, acc1); \
    AGR(r1d, tw); acc1 = fmaf(tw, hv.w, acc1); \
    AGR(r2a, tw); acc2 = fmaf(tw, hv.x, acc2); \
    AGR(r2b, tw); acc2 = fmaf(tw, hv.y, acc2); \
    AGR(r2c, tw); acc2 = fmaf(tw, hv.z, acc2); \
    AGR(r2d, tw); acc2 = fmaf(tw, hv.w, acc2); \
  } while (0)

// indirection so the K-lists expand into individual macro args
#define LOADK(...) LOADK_(__VA_ARGS__)
#define GEMVK(...) GEMVK_(__VA_ARGS__)

#define KL0 "a0","a1","a2","a3",    "a32","a33","a34","a35", "a64","a65","a66","a67"
#define KL1 "a4","a5","a6","a7",    "a36","a37","a38","a39", "a68","a69","a70","a71"
#define KL2 "a8","a9","a10","a11",  "a40","a41","a42","a43", "a72","a73","a74","a75"
#define KL3 "a12","a13","a14","a15","a44","a45","a46","a47", "a76","a77","a78","a79"
#define KL4 "a16","a17","a18","a19","a48","a49","a50","a51", "a80","a81","a82","a83"
#define KL5 "a20","a21","a22","a23","a52","a53","a54","a55", "a84","a85","a86","a87"
#define KL6 "a24","a25","a26","a27","a56","a57","a58","a59", "a88","a89","a90","a91"
#define KL7 "a28","a29","a30","a31","a60","a61","a62","a63", "a92","a93","a94","a95"

__global__ __launch_bounds__(512, 1) void gru_scan(
    const float* __restrict__ w_hh,   // [6144][2048]
    const float* __restrict__ b_hh,   // [6144]
    const float* __restrict__ gi,     // [2048][6144]
    float* __restrict__ hs,           // [2048][2048]
    unsigned long long* mb)           // [2][2048] (value|tag)
{
  __shared__ __align__(16) float hbuf[H_N];
  const int g   = blockIdx.x;
  const int tid = threadIdx.x;
  const int w   = tid >> 6;
  const int l   = tid & 63;
  const int l4  = l * 4;
  const int j   = (g << 3) + w;       // owned h index

  // one-time weight load into physical AGPRs (lane l covers cols k*256+l*4..+4)
  {
    const float* p0 = w_hh + (size_t)j * H_N;
    const float* p1 = w_hh + (size_t)(H_N + j) * H_N;
    const float* p2 = w_hh + (size_t)(2 * H_N + j) * H_N;
    LOADK(0, KL0); LOADK(1, KL1); LOADK(2, KL2); LOADK(3, KL3);
    LOADK(4, KL4); LOADK(5, KL5); LOADK(6, KL6); LOADK(7, KL7);
  }
  const float bh0 = b_hh[j], bh1 = b_hh[H_N + j], bh2 = b_hh[2 * H_N + j];
  float hprev = 0.f;

  for (int t = 0; t < P_N; ++t) {
    // gi prefetch (independent of mailbox; hides latency behind the poll)
    const float ir  = gi[(size_t)t * G3H + j];
    const float iz  = gi[(size_t)t * G3H + H_N + j];
    const float inn = gi[(size_t)t * G3H + 2 * H_N + j];

    float acc0 = 0.f, acc1 = 0.f, acc2 = 0.f;
    if (t > 0) {
      // poll mailbox for h_{t-1}: thread tid owns slots tid*4..+4
      unsigned long long* src = mb + (size_t)((t - 1) & 1) * H_N + tid * 4;
      float h0 = 0.f, h1 = 0.f, h2 = 0.f, h3 = 0.f;
      unsigned pend = 0xFu;
      const unsigned tag = (unsigned)t;
      while (pend) {
#pragma unroll
        for (int q = 0; q < 4; ++q) {
          if (pend & (1u << q)) {
            unsigned long long v =
                __hip_atomic_load(src + q, __ATOMIC_RELAXED, __HIP_MEMORY_SCOPE_AGENT);
            if ((unsigned)(v >> 32) == tag) {
              float f = __uint_as_float((unsigned)(v & 0xffffffffull));
              if (q == 0) h0 = f; else if (q == 1) h1 = f;
              else if (q == 2) h2 = f; else h3 = f;
              pend &= ~(1u << q);
            }
          }
        }
        if (pend) __builtin_amdgcn_s_sleep(1);
      }
      __syncthreads();   // all waves done reading hbuf from step t-1
      *(float4*)&hbuf[tid * 4] = make_float4(h0, h1, h2, h3);
      __syncthreads();   // hbuf fully populated

      // GEMV: 3 gate rows x 2048 cols, 32 cols/lane; weights from phys AGPRs
      GEMVK(0, KL0); GEMVK(1, KL1); GEMVK(2, KL2); GEMVK(3, KL3);
      GEMVK(4, KL4); GEMVK(5, KL5); GEMVK(6, KL6); GEMVK(7, KL7);

#pragma unroll
      for (int off = 32; off > 0; off >>= 1) {
        acc0 += __shfl_xor(acc0, off);
        acc1 += __shfl_xor(acc1, off);
        acc2 += __shfl_xor(acc2, off);
      }
    }

    // gates (all lanes redundantly; values are wave-uniform after butterfly)
    const float r = 1.f / (1.f + __expf(-(ir + acc0 + bh0)));
    const float z = 1.f / (1.f + __expf(-(iz + acc1 + bh1)));
    const float narg = inn + r * (acc2 + bh2);
    const float e2 = __expf(2.f * narg);              // inline tanh, no libcall
    const float n = (e2 - 1.f) / (e2 + 1.f);
    const float hnew = (1.f - z) * n + z * hprev;
    hprev = hnew;

    if (l == 0) {
      hs[(size_t)t * H_N + j] = hnew;  // plain store; consumed by later kernels
      unsigned long long pk = ((unsigned long long)(unsigned)(t + 1) << 32) |
                              (unsigned long long)__float_as_uint(hnew);
      __hip_atomic_store(mb + (size_t)(t & 1) * H_N + j, pk,
                         __ATOMIC_RELAXED, __HIP_MEMORY_SCOPE_AGENT);
    }
  }
}

// ---------------------------------------------------------------------------
// Kernel 3: acts = leaky(hs @ ff_w.T + ff_b)  -> acts[0][p], acts[1][p]
// ---------------------------------------------------------------------------
__global__ __launch_bounds__(512) void acts_kernel(
    const float* __restrict__ hs, const float* __restrict__ ff_w,
    const float* __restrict__ ff_b, float* __restrict__ acts)
{
  const int w = threadIdx.x >> 6, l = threadIdx.x & 63;
  const int p = blockIdx.x * 8 + w;
  const float* hrow = hs + (size_t)p * H_N;
  float sa = 0.f, sd = 0.f;
#pragma unroll
  for (int k = 0; k < 8; ++k) {
    float4 hv = *(const float4*)(hrow + k * 256 + l * 4);
    float4 fa = *(const float4*)(ff_w + k * 256 + l * 4);
    float4 fd = *(const float4*)(ff_w + H_N + k * 256 + l * 4);
    sa += hv.x * fa.x + hv.y * fa.y + hv.z * fa.z + hv.w * fa.w;
    sd += hv.x * fd.x + hv.y * fd.y + hv.z * fd.z + hv.w * fd.w;
  }
  sa = wave_sum(sa); sd = wave_sum(sd);
  if (l == 0) {
    float a = sa + ff_b[0];
    float d = sd + ff_b[1];
    a = (a >= 0.f) ? a : 0.01f * a;
    d = (d >= 0.f) ? d : 0.01f * d;
    acts[p] = a;
    acts[P_N + p] = d;
  }
}

// ---------------------------------------------------------------------------
// Kernel 4: two softmaxes over 2048 -> wts[0][p], wts[1][p]
// ---------------------------------------------------------------------------
__global__ __launch_bounds__(256) void softmax_kernel(
    const float* __restrict__ acts, float* __restrict__ wts)
{
  __shared__ float red[4];
  __shared__ float bcast;
  const int tid = threadIdx.x;
  const int w = tid >> 6, l = tid & 63;
  for (int c = 0; c < 2; ++c) {
    const float* x = acts + c * P_N;
    float* y = wts + c * P_N;
    float m = -3.4e38f;
    for (int i = tid; i < P_N; i += 256) m = fmaxf(m, x[i]);
    m = wave_max(m);
    if (l == 0) red[w] = m;
    __syncthreads();
    if (tid == 0) bcast = fmaxf(fmaxf(red[0], red[1]), fmaxf(red[2], red[3]));
    __syncthreads();
    const float M = bcast;
    float s = 0.f;
    for (int i = tid; i < P_N; i += 256) {
      float e = __expf(x[i] - M);
      y[i] = e;
      s += e;
    }
    s = wave_sum(s);
    __syncthreads();            // everyone read bcast/red before reuse
    if (l == 0) red[w] = s;
    __syncthreads();
    if (tid == 0) bcast = 1.f / (red[0] + red[1] + red[2] + red[3]);
    __syncthreads();
    const float inv = bcast;
    for (int i = tid; i < P_N; i += 256) y[i] *= inv;
    __syncthreads();
  }
}

// ---------------------------------------------------------------------------
// Kernel 5: attention pooling: att[0][:] = a_w @ hs, att[1][:] = d_w @ hs
// ---------------------------------------------------------------------------
__global__ __launch_bounds__(256) void pool_kernel(
    const float* __restrict__ hs, const float* __restrict__ wts,
    float* __restrict__ att)
{
  const int g = blockIdx.x;
  const int tid = threadIdx.x;
  const int c0 = tid * 8;
  float aa[8] = {0, 0, 0, 0, 0, 0, 0, 0};
  float dd[8] = {0, 0, 0, 0, 0, 0, 0, 0};
  for (int r = 0; r < 16; ++r) {
    const int p = g * 16 + r;
    const float wa = wts[p];
    const float wd = wts[P_N + p];
    const float* hp = hs + (size_t)p * H_N + c0;
    float4 h0 = *(const float4*)hp;
    float4 h1 = *(const float4*)(hp + 4);
    aa[0] = fmaf(wa, h0.x, aa[0]); aa[1] = fmaf(wa, h0.y, aa[1]);
    aa[2] = fmaf(wa, h0.z, aa[2]); aa[3] = fmaf(wa, h0.w, aa[3]);
    aa[4] = fmaf(wa, h1.x, aa[4]); aa[5] = fmaf(wa, h1.y, aa[5]);
    aa[6] = fmaf(wa, h1.z, aa[6]); aa[7] = fmaf(wa, h1.w, aa[7]);
    dd[0] = fmaf(wd, h0.x, dd[0]); dd[1] = fmaf(wd, h0.y, dd[1]);
    dd[2] = fmaf(wd, h0.z, dd[2]); dd[3] = fmaf(wd, h0.w, dd[3]);
    dd[4] = fmaf(wd, h1.x, dd[4]); dd[5] = fmaf(wd, h1.y, dd[5]);
    dd[6] = fmaf(wd, h1.z, dd[6]); dd[7] = fmaf(wd, h1.w, dd[7]);
  }
#pragma unroll
  for (int q = 0; q < 8; ++q) {
    atomicAdd(&att[c0 + q], aa[q]);
    atomicAdd(&att[H_N + c0 + q], dd[q]);
  }
}

// ---------------------------------------------------------------------------
// Kernel 6: heads: a_pol(3), d_pol(3), v(1) -> d_out[0..6]
// ---------------------------------------------------------------------------
__global__ __launch_bounds__(512) void head_kernel(
    const float* __restrict__ att,
    const float* __restrict__ ap_w, const float* __restrict__ ap_b,
    const float* __restrict__ dp_w, const float* __restrict__ dp_b,
    const float* __restrict__ v_w, const float* __restrict__ v_b,
    float* __restrict__ out)
{
  const int w = threadIdx.x >> 6, l = threadIdx.x & 63;
  if (w >= 7) return;
  float s = 0.f;
  if (w < 3) {
    const float* m = ap_w + (size_t)w * H_N;
    for (int k = 0; k < 32; ++k) { int i = k * 64 + l; s += att[i] * m[i]; }
  } else if (w < 6) {
    const float* m = dp_w + (size_t)(w - 3) * H_N;
    for (int k = 0; k < 32; ++k) { int i = k * 64 + l; s += att[H_N + i] * m[i]; }
  } else {
    for (int k = 0; k < 32; ++k) { int i = k * 64 + l; s += (att[i] + att[H_N + i]) * v_w[i]; }
  }
  s = wave_sum(s);
  if (l == 0) {
    float b = (w < 3) ? ap_b[w] : ((w < 6) ? dp_b[w - 3] : v_b[0]);
    out[w] = s + b;
  }
}

// ---------------------------------------------------------------------------
extern "C" void kernel_launch(void* const* d_in, const int* in_sizes, int n_in,
                              void* d_out, int out_size, void* d_ws, size_t ws_size,
                              hipStream_t stream) {
  const float* obs  = (const float*)d_in[0];
  // d_in[1] messages, d_in[2] embeddings, d_in[3] h : unused by reference
  const float* w_ih = (const float*)d_in[4];
  const float* w_hh = (const float*)d_in[5];
  const float* b_ih = (const float*)d_in[6];
  const float* b_hh = (const float*)d_in[7];
  const float* ff_w = (const float*)d_in[8];
  const float* ff_b = (const float*)d_in[9];
  const float* ap_w = (const float*)d_in[10];
  const float* ap_b = (const float*)d_in[11];
  const float* dp_w = (const float*)d_in[12];
  const float* dp_b = (const float*)d_in[13];
  const float* v_w  = (const float*)d_in[14];
  const float* v_b  = (const float*)d_in[15];
  float* out = (float*)d_out;

  // workspace layout (fp32 unless noted): gi[2048*6144] | hs[2048*2048] |
  // mb[2*2048] u64 | acts[2*2048] | wts[2*2048] | att[2*2048]   (~67.2 MB)
  float* gi = (float*)d_ws;
  float* hs = gi + (size_t)P_N * G3H;
  unsigned long long* mb = (unsigned long long*)(hs + (size_t)P_N * H_N);
  float* acts = (float*)(mb + 2 * H_N);
  float* wts  = acts + 2 * P_N;
  float* att  = wts + 2 * P_N;

  hipMemsetAsync(mb, 0, 2 * H_N * sizeof(unsigned long long), stream);  // clear tags
  hipMemsetAsync(att, 0, 2 * H_N * sizeof(float), stream);              // atomic accum

  gi_gemm<<<dim3(G3H / 128, P_N / 128), 256, 0, stream>>>(obs, w_ih, b_ih, gi);
  gru_scan<<<256, 512, 0, stream>>>(w_hh, b_hh, gi, hs, mb);
  acts_kernel<<<P_N / 8, 512, 0, stream>>>(hs, ff_w, ff_b, acts);
  softmax_kernel<<<1, 256, 0, stream>>>(acts, wts);
  pool_kernel<<<128, 256, 0, stream>>>(hs, wts, att);
  head_kernel<<<1, 512, 0, stream>>>(att, ap_w, ap_b, dp_w, dp_b, v_w, v_b, out);
}

// Round 6
// 8768.590 us; speedup vs baseline: 1.2422x; 1.2422x over previous
//
#include <hip/hip_runtime.h>
#include <cstdint>
#include <cstddef>

#define P_N  2048
#define OBS_N 512
#define H_N  2048
#define G3H  6144

__device__ __forceinline__ float wave_sum(float v) {
#pragma unroll
  for (int off = 32; off > 0; off >>= 1) v += __shfl_xor(v, off);
  return v;
}
__device__ __forceinline__ float wave_max(float v) {
#pragma unroll
  for (int off = 32; off > 0; off >>= 1) v = fmaxf(v, __shfl_xor(v, off));
  return v;
}

// ---------------------------------------------------------------------------
// Kernel 1: gi = obs @ w_ih.T + b_ih   (fp32, 128x128 tile, 8x8 per thread)
// ---------------------------------------------------------------------------
__global__ __launch_bounds__(256, 2) void gi_gemm(
    const float* __restrict__ A,    // obs [2048][512]
    const float* __restrict__ B,    // w_ih [6144][512]
    const float* __restrict__ bias, // b_ih [6144]
    float* __restrict__ C)          // gi [2048][6144]
{
  constexpr int BM = 128, BK = 32, LDP = BM + 4;
  __shared__ float As[BK][LDP];
  __shared__ float Bs[BK][LDP];
  const int tid = threadIdx.x;
  const int bm = blockIdx.y * BM;
  const int bn = blockIdx.x * BM;
  const int tx = tid & 15, ty = tid >> 4;
  const int lrow = tid >> 3;          // 0..31
  const int lk4  = (tid & 7) << 2;    // 0..28

  float acc[8][8];
#pragma unroll
  for (int i = 0; i < 8; ++i)
#pragma unroll
    for (int j = 0; j < 8; ++j) acc[i][j] = 0.f;

  for (int k0 = 0; k0 < OBS_N; k0 += BK) {
#pragma unroll
    for (int i = 0; i < 4; ++i) {
      const int r = lrow + 32 * i;
      float4 av = *(const float4*)(A + (size_t)(bm + r) * OBS_N + k0 + lk4);
      float4 bv = *(const float4*)(B + (size_t)(bn + r) * OBS_N + k0 + lk4);
      As[lk4 + 0][r] = av.x; As[lk4 + 1][r] = av.y;
      As[lk4 + 2][r] = av.z; As[lk4 + 3][r] = av.w;
      Bs[lk4 + 0][r] = bv.x; Bs[lk4 + 1][r] = bv.y;
      Bs[lk4 + 2][r] = bv.z; Bs[lk4 + 3][r] = bv.w;
    }
    __syncthreads();
#pragma unroll
    for (int k = 0; k < BK; ++k) {
      float4 a0 = *(const float4*)&As[k][ty * 4];
      float4 a1 = *(const float4*)&As[k][64 + ty * 4];
      float4 b0 = *(const float4*)&Bs[k][tx * 4];
      float4 b1 = *(const float4*)&Bs[k][64 + tx * 4];
      float a[8] = {a0.x, a0.y, a0.z, a0.w, a1.x, a1.y, a1.z, a1.w};
      float b[8] = {b0.x, b0.y, b0.z, b0.w, b1.x, b1.y, b1.z, b1.w};
#pragma unroll
      for (int i = 0; i < 8; ++i)
#pragma unroll
        for (int j = 0; j < 8; ++j)
          acc[i][j] = fmaf(a[i], b[j], acc[i][j]);
    }
    __syncthreads();
  }

  float4 bs0 = *(const float4*)(bias + bn + tx * 4);
  float4 bs1 = *(const float4*)(bias + bn + 64 + tx * 4);
  const float bb[8] = {bs0.x, bs0.y, bs0.z, bs0.w, bs1.x, bs1.y, bs1.z, bs1.w};
#pragma unroll
  for (int i = 0; i < 8; ++i) {
    const int row = bm + ((i < 4) ? (ty * 4 + i) : (64 + ty * 4 + i - 4));
    float4 o0 = {acc[i][0] + bb[0], acc[i][1] + bb[1], acc[i][2] + bb[2], acc[i][3] + bb[3]};
    float4 o1 = {acc[i][4] + bb[4], acc[i][5] + bb[5], acc[i][6] + bb[6], acc[i][7] + bb[7]};
    *(float4*)(C + (size_t)row * G3H + bn + tx * 4) = o0;
    *(float4*)(C + (size_t)row * G3H + bn + 64 + tx * 4) = o1;
  }
}

// ---------------------------------------------------------------------------
// Kernel 2: sequential GRU scan. 256 persistent WGs x 512 threads, 1 WG/CU.
// Weights in PHYSICAL AGPRs a0..a95 (R5 scheme, proven correct).
//
// R6 handshake restructure (R5 proved weights were never the bottleneck:
// physical-AGPR residency left dur at 5.2 us/step):
//  - coarse per-WG flags: tid0 stores flag[par][g]=t+1 after __syncthreads
//    drains all 8 mailbox stores. Consumers poll ONLY the 256 flags with a
//    single wave (2 u64 loads/lane/round) instead of all 512 threads
//    re-reading 2048 slots every round (~4 MB/round chip-wide -> saturated
//    L3, ~20 poll rounds/step, VALUBusy 21%).
//  - tagged slot values remain the correctness ground truth: one read after
//    flag detect, rare tag-mismatch retry loop. Flag racing ahead of data
//    costs a retry, never wrongness.
//  - hs rows written coalesced (float4 from hbuf, rotating writer WG)
//    instead of 2048 scattered 4B stores/step (kills partial-line RMW).
// ---------------------------------------------------------------------------
#define AGW(reg, val) \
  asm volatile("v_accvgpr_write_b32 " reg ", %0" :: "v"(val) : reg)
#define AGR(reg, dst) \
  asm volatile("v_accvgpr_read_b32 %0, " reg : "=v"(dst) :: reg)

#define LOADK_(koff, r0a,r0b,r0c,r0d, r1a,r1b,r1c,r1d, r2a,r2b,r2c,r2d) do { \
    float4 A_ = *(const float4*)(p0 + (koff) * 256 + l4); \
    float4 B_ = *(const float4*)(p1 + (koff) * 256 + l4); \
    float4 C_ = *(const float4*)(p2 + (koff) * 256 + l4); \
    AGW(r0a, A_.x); AGW(r0b, A_.y); AGW(r0c, A_.z); AGW(r0d, A_.w); \
    AGW(r1a, B_.x); AGW(r1b, B_.y); AGW(r1c, B_.z); AGW(r1d, B_.w); \
    AGW(r2a, C_.x); AGW(r2b, C_.y); AGW(r2c, C_.z); AGW(r2d, C_.w); \
  } while (0)

#define GEMVK_(koff, r0a,r0b,r0c,r0d, r1a,r1b,r1c,r1d, r2a,r2b,r2c,r2d) do { \
    float4 hv = *(const float4*)&hbuf[(koff) * 256 + l4]; \
    float tw; \
    AGR(r0a, tw); acc0 = fmaf(tw, hv.x, acc0); \
    AGR(r0b, tw); acc0 = fmaf(tw, hv.y, acc0); \
    AGR(r0c, tw); acc0 = fmaf(tw, hv.z, acc0); \
    AGR(r0d, tw); acc0 = fmaf(tw, hv.w, acc0); \
    AGR(r1a, tw); acc1 = fmaf(tw, hv.x, acc1); \
    AGR(r1b, tw); acc1 = fmaf(tw, hv.y, acc1); \
    AGR(r1c, tw); acc1 = fmaf(tw, hv.z, acc1); \
    AGR(r1d, tw); acc1 = fmaf(tw, hv.w, acc1); \
    AGR(r2a, tw); acc2 = fmaf(tw, hv.x, acc2); \
    AGR(r2b, tw); acc2 = fmaf(tw, hv.y, acc2); \
    AGR(r2c, tw); acc2 = fmaf(tw, hv.z, acc2); \
    AGR(r2d, tw); acc2 = fmaf(tw, hv.w, acc2); \
  } while (0)

#define LOADK(...) LOADK_(__VA_ARGS__)
#define GEMVK(...) GEMVK_(__VA_ARGS__)

#define KL0 "a0","a1","a2","a3",    "a32","a33","a34","a35", "a64","a65","a66","a67"
#define KL1 "a4","a5","a6","a7",    "a36","a37","a38","a39", "a68","a69","a70","a71"
#define KL2 "a8","a9","a10","a11",  "a40","a41","a42","a43", "a72","a73","a74","a75"
#define KL3 "a12","a13","a14","a15","a44","a45","a46","a47", "a76","a77","a78","a79"
#define KL4 "a16","a17","a18","a19","a48","a49","a50","a51", "a80","a81","a82","a83"
#define KL5 "a20","a21","a22","a23","a52","a53","a54","a55", "a84","a85","a86","a87"
#define KL6 "a24","a25","a26","a27","a56","a57","a58","a59", "a88","a89","a90","a91"
#define KL7 "a28","a29","a30","a31","a60","a61","a62","a63", "a92","a93","a94","a95"

__global__ __launch_bounds__(512, 1) void gru_scan(
    const float* __restrict__ w_hh,   // [6144][2048]
    const float* __restrict__ b_hh,   // [6144]
    const float* __restrict__ gi,     // [2048][6144]
    float* __restrict__ hs,           // [2048][2048]
    unsigned long long* mb,           // [2][2048] (tag|value)
    unsigned* flags)                  // [2][256]  per-WG step flags
{
  __shared__ __align__(16) float hbuf[H_N];
  const int g   = blockIdx.x;
  const int tid = threadIdx.x;
  const int w   = tid >> 6;
  const int l   = tid & 63;
  const int l4  = l * 4;
  const int j   = (g << 3) + w;       // owned h index

  // one-time weight load into physical AGPRs (lane l covers cols k*256+l*4..+4)
  {
    const float* p0 = w_hh + (size_t)j * H_N;
    const float* p1 = w_hh + (size_t)(H_N + j) * H_N;
    const float* p2 = w_hh + (size_t)(2 * H_N + j) * H_N;
    LOADK(0, KL0); LOADK(1, KL1); LOADK(2, KL2); LOADK(3, KL3);
    LOADK(4, KL4); LOADK(5, KL5); LOADK(6, KL6); LOADK(7, KL7);
  }
  const float bh0 = b_hh[j], bh1 = b_hh[H_N + j], bh2 = b_hh[2 * H_N + j];
  float hprev = 0.f;

  for (int t = 0; t < P_N; ++t) {
    // gi prefetch (independent of handshake; hides HBM latency behind poll)
    const float ir  = gi[(size_t)t * G3H + j];
    const float iz  = gi[(size_t)t * G3H + H_N + j];
    const float inn = gi[(size_t)t * G3H + 2 * H_N + j];

    float acc0 = 0.f, acc1 = 0.f, acc2 = 0.f;
    if (t > 0) {
      const unsigned tag = (unsigned)t;          // h_{t-1} carries tag t
      const int par = (t - 1) & 1;

      // ---- flag poll: wave 0 only, 2 u64 loads/lane/round over 256 flags
      if (w == 0) {
        const unsigned long long exp2 =
            (unsigned long long)tag * 0x100000001ULL;   // tag | tag<<32
        unsigned long long* fp =
            (unsigned long long*)(flags + (size_t)par * 256) + 2 * l;
        for (;;) {
          unsigned long long f0 =
              __hip_atomic_load(fp + 0, __ATOMIC_RELAXED, __HIP_MEMORY_SCOPE_AGENT);
          unsigned long long f1 =
              __hip_atomic_load(fp + 1, __ATOMIC_RELAXED, __HIP_MEMORY_SCOPE_AGENT);
          if (__all(f0 == exp2 && f1 == exp2)) break;
          __builtin_amdgcn_s_sleep(1);
        }
      }
      __syncthreads();   // release waves 1-7 once flags confirm publication

      // ---- single tagged slot read (rare retry on flag/data race)
      unsigned long long* src = mb + (size_t)par * H_N + tid * 4;
      float h0 = 0.f, h1 = 0.f, h2 = 0.f, h3 = 0.f;
      unsigned pend = 0xFu;
      while (pend) {
#pragma unroll
        for (int q = 0; q < 4; ++q) {
          if (pend & (1u << q)) {
            unsigned long long v =
                __hip_atomic_load(src + q, __ATOMIC_RELAXED, __HIP_MEMORY_SCOPE_AGENT);
            if ((unsigned)(v >> 32) == tag) {
              float f = __uint_as_float((unsigned)(v & 0xffffffffull));
              if (q == 0) h0 = f; else if (q == 1) h1 = f;
              else if (q == 2) h2 = f; else h3 = f;
              pend &= ~(1u << q);
            }
          }
        }
        if (pend) __builtin_amdgcn_s_sleep(1);
      }
      *(float4*)&hbuf[tid * 4] = make_float4(h0, h1, h2, h3);
      __syncthreads();   // hbuf fully populated

      // ---- coalesced hs row write: row t-1 by rotating writer WG
      if (g == ((t - 1) & 255)) {
        *(float4*)(hs + (size_t)(t - 1) * H_N + tid * 4) =
            *(const float4*)&hbuf[tid * 4];
      }

      // ---- GEMV: 3 gate rows x 2048 cols, weights from phys AGPRs
      GEMVK(0, KL0); GEMVK(1, KL1); GEMVK(2, KL2); GEMVK(3, KL3);
      GEMVK(4, KL4); GEMVK(5, KL5); GEMVK(6, KL6); GEMVK(7, KL7);

#pragma unroll
      for (int off = 32; off > 0; off >>= 1) {
        acc0 += __shfl_xor(acc0, off);
        acc1 += __shfl_xor(acc1, off);
        acc2 += __shfl_xor(acc2, off);
      }
    }

    // gates (all lanes redundantly; values are wave-uniform after butterfly)
    const float r = 1.f / (1.f + __expf(-(ir + acc0 + bh0)));
    const float z = 1.f / (1.f + __expf(-(iz + acc1 + bh1)));
    const float narg = inn + r * (acc2 + bh2);
    const float e2 = __expf(2.f * narg);              // inline tanh, no libcall
    const float n = (e2 - 1.f) / (e2 + 1.f);
    const float hnew = (1.f - z) * n + z * hprev;
    hprev = hnew;

    // publish h_t: 8 tagged slot stores, then (after vmcnt drain) one flag
    if (l == 0) {
      unsigned long long pk = ((unsigned long long)(unsigned)(t + 1) << 32) |
                              (unsigned long long)__float_as_uint(hnew);
      __hip_atomic_store(mb + (size_t)(t & 1) * H_N + j, pk,
                         __ATOMIC_RELAXED, __HIP_MEMORY_SCOPE_AGENT);
    }
    __syncthreads();   // drains vmcnt(0): all 8 slot stores complete
    if (tid == 0) {
      __hip_atomic_store(flags + (size_t)(t & 1) * 256 + g, (unsigned)(t + 1),
                         __ATOMIC_RELAXED, __HIP_MEMORY_SCOPE_AGENT);
    }
  }

  // final hs row (2047) — one-time scattered store per wave
  if (l == 0) hs[(size_t)(P_N - 1) * H_N + j] = hprev;
}

// ---------------------------------------------------------------------------
// Kernel 3: acts = leaky(hs @ ff_w.T + ff_b)  -> acts[0][p], acts[1][p]
// ---------------------------------------------------------------------------
__global__ __launch_bounds__(512) void acts_kernel(
    const float* __restrict__ hs, const float* __restrict__ ff_w,
    const float* __restrict__ ff_b, float* __restrict__ acts)
{
  const int w = threadIdx.x >> 6, l = threadIdx.x & 63;
  const int p = blockIdx.x * 8 + w;
  const float* hrow = hs + (size_t)p * H_N;
  float sa = 0.f, sd = 0.f;
#pragma unroll
  for (int k = 0; k < 8; ++k) {
    float4 hv = *(const float4*)(hrow + k * 256 + l * 4);
    float4 fa = *(const float4*)(ff_w + k * 256 + l * 4);
    float4 fd = *(const float4*)(ff_w + H_N + k * 256 + l * 4);
    sa += hv.x * fa.x + hv.y * fa.y + hv.z * fa.z + hv.w * fa.w;
    sd += hv.x * fd.x + hv.y * fd.y + hv.z * fd.z + hv.w * fd.w;
  }
  sa = wave_sum(sa); sd = wave_sum(sd);
  if (l == 0) {
    float a = sa + ff_b[0];
    float d = sd + ff_b[1];
    a = (a >= 0.f) ? a : 0.01f * a;
    d = (d >= 0.f) ? d : 0.01f * d;
    acts[p] = a;
    acts[P_N + p] = d;
  }
}

// ---------------------------------------------------------------------------
// Kernel 4: two softmaxes over 2048 -> wts[0][p], wts[1][p]
// ---------------------------------------------------------------------------
__global__ __launch_bounds__(256) void softmax_kernel(
    const float* __restrict__ acts, float* __restrict__ wts)
{
  __shared__ float red[4];
  __shared__ float bcast;
  const int tid = threadIdx.x;
  const int w = tid >> 6, l = tid & 63;
  for (int c = 0; c < 2; ++c) {
    const float* x = acts + c * P_N;
    float* y = wts + c * P_N;
    float m = -3.4e38f;
    for (int i = tid; i < P_N; i += 256) m = fmaxf(m, x[i]);
    m = wave_max(m);
    if (l == 0) red[w] = m;
    __syncthreads();
    if (tid == 0) bcast = fmaxf(fmaxf(red[0], red[1]), fmaxf(red[2], red[3]));
    __syncthreads();
    const float M = bcast;
    float s = 0.f;
    for (int i = tid; i < P_N; i += 256) {
      float e = __expf(x[i] - M);
      y[i] = e;
      s += e;
    }
    s = wave_sum(s);
    __syncthreads();            // everyone read bcast/red before reuse
    if (l == 0) red[w] = s;
    __syncthreads();
    if (tid == 0) bcast = 1.f / (red[0] + red[1] + red[2] + red[3]);
    __syncthreads();
    const float inv = bcast;
    for (int i = tid; i < P_N; i += 256) y[i] *= inv;
    __syncthreads();
  }
}

// ---------------------------------------------------------------------------
// Kernel 5: attention pooling: att[0][:] = a_w @ hs, att[1][:] = d_w @ hs
// ---------------------------------------------------------------------------
__global__ __launch_bounds__(256) void pool_kernel(
    const float* __restrict__ hs, const float* __restrict__ wts,
    float* __restrict__ att)
{
  const int g = blockIdx.x;
  const int tid = threadIdx.x;
  const int c0 = tid * 8;
  float aa[8] = {0, 0, 0, 0, 0, 0, 0, 0};
  float dd[8] = {0, 0, 0, 0, 0, 0, 0, 0};
  for (int r = 0; r < 16; ++r) {
    const int p = g * 16 + r;
    const float wa = wts[p];
    const float wd = wts[P_N + p];
    const float* hp = hs + (size_t)p * H_N + c0;
    float4 h0 = *(const float4*)hp;
    float4 h1 = *(const float4*)(hp + 4);
    aa[0] = fmaf(wa, h0.x, aa[0]); aa[1] = fmaf(wa, h0.y, aa[1]);
    aa[2] = fmaf(wa, h0.z, aa[2]); aa[3] = fmaf(wa, h0.w, aa[3]);
    aa[4] = fmaf(wa, h1.x, aa[4]); aa[5] = fmaf(wa, h1.y, aa[5]);
    aa[6] = fmaf(wa, h1.z, aa[6]); aa[7] = fmaf(wa, h1.w, aa[7]);
    dd[0] = fmaf(wd, h0.x, dd[0]); dd[1] = fmaf(wd, h0.y, dd[1]);
    dd[2] = fmaf(wd, h0.z, dd[2]); dd[3] = fmaf(wd, h0.w, dd[3]);
    dd[4] = fmaf(wd, h1.x, dd[4]); dd[5] = fmaf(wd, h1.y, dd[5]);
    dd[6] = fmaf(wd, h1.z, dd[6]); dd[7] = fmaf(wd, h1.w, dd[7]);
  }
#pragma unroll
  for (int q = 0; q < 8; ++q) {
    atomicAdd(&att[c0 + q], aa[q]);
    atomicAdd(&att[H_N + c0 + q], dd[q]);
  }
}

// ---------------------------------------------------------------------------
// Kernel 6: heads: a_pol(3), d_pol(3), v(1) -> d_out[0..6]
// ---------------------------------------------------------------------------
__global__ __launch_bounds__(512) void head_kernel(
    const float* __restrict__ att,
    const float* __restrict__ ap_w, const float* __restrict__ ap_b,
    const float* __restrict__ dp_w, const float* __restrict__ dp_b,
    const float* __restrict__ v_w, const float* __restrict__ v_b,
    float* __restrict__ out)
{
  const int w = threadIdx.x >> 6, l = threadIdx.x & 63;
  if (w >= 7) return;
  float s = 0.f;
  if (w < 3) {
    const float* m = ap_w + (size_t)w * H_N;
    for (int k = 0; k < 32; ++k) { int i = k * 64 + l; s += att[i] * m[i]; }
  } else if (w < 6) {
    const float* m = dp_w + (size_t)(w - 3) * H_N;
    for (int k = 0; k < 32; ++k) { int i = k * 64 + l; s += att[H_N + i] * m[i]; }
  } else {
    for (int k = 0; k < 32; ++k) { int i = k * 64 + l; s += (att[i] + att[H_N + i]) * v_w[i]; }
  }
  s = wave_sum(s);
  if (l == 0) {
    float b = (w < 3) ? ap_b[w] : ((w < 6) ? dp_b[w - 3] : v_b[0]);
    out[w] = s + b;
  }
}

// ---------------------------------------------------------------------------
extern "C" void kernel_launch(void* const* d_in, const int* in_sizes, int n_in,
                              void* d_out, int out_size, void* d_ws, size_t ws_size,
                              hipStream_t stream) {
  const float* obs  = (const float*)d_in[0];
  // d_in[1] messages, d_in[2] embeddings, d_in[3] h : unused by reference
  const float* w_ih = (const float*)d_in[4];
  const float* w_hh = (const float*)d_in[5];
  const float* b_ih = (const float*)d_in[6];
  const float* b_hh = (const float*)d_in[7];
  const float* ff_w = (const float*)d_in[8];
  const float* ff_b = (const float*)d_in[9];
  const float* ap_w = (const float*)d_in[10];
  const float* ap_b = (const float*)d_in[11];
  const float* dp_w = (const float*)d_in[12];
  const float* dp_b = (const float*)d_in[13];
  const float* v_w  = (const float*)d_in[14];
  const float* v_b  = (const float*)d_in[15];
  float* out = (float*)d_out;

  // workspace layout (fp32 unless noted): gi[2048*6144] | hs[2048*2048] |
  // mb[2*2048] u64 | flags[2*256] u32 | acts[2*2048] | wts[2*2048] | att[2*2048]
  float* gi = (float*)d_ws;
  float* hs = gi + (size_t)P_N * G3H;
  unsigned long long* mb = (unsigned long long*)(hs + (size_t)P_N * H_N);
  unsigned* flags = (unsigned*)(mb + 2 * H_N);
  float* acts = (float*)(flags + 2 * 256);
  float* wts  = acts + 2 * P_N;
  float* att  = wts + 2 * P_N;

  // clear mailbox tags + flags (contiguous) and the atomic accumulator
  hipMemsetAsync(mb, 0, 2 * H_N * sizeof(unsigned long long) + 2 * 256 * sizeof(unsigned), stream);
  hipMemsetAsync(att, 0, 2 * H_N * sizeof(float), stream);

  gi_gemm<<<dim3(G3H / 128, P_N / 128), 256, 0, stream>>>(obs, w_ih, b_ih, gi);
  gru_scan<<<256, 512, 0, stream>>>(w_hh, b_hh, gi, hs, mb, flags);
  acts_kernel<<<P_N / 8, 512, 0, stream>>>(hs, ff_w, ff_b, acts);
  softmax_kernel<<<1, 256, 0, stream>>>(acts, wts);
  pool_kernel<<<128, 256, 0, stream>>>(hs, wts, att);
  head_kernel<<<1, 512, 0, stream>>>(att, ap_w, ap_b, dp_w, dp_b, v_w, v_b, out);
}